// Round 15
// baseline (39.598 us; speedup 1.0000x reference)
//
#include <hip/hip_runtime.h>
#include <hip/hip_fp16.h>

#define B_ 2048
#define F_ 4096
#define C_ 8192
#define T_ 8
#define K_ 1024
#define S_ 8
#define RROWS 8
#define TPB 1024

// packed f16 max: ROCm 7.2 lacks __hmax2; gfx950 has v_pk_max_f16
__device__ __forceinline__ __half2 h2max(__half2 a, __half2 b) {
    unsigned ua = *(unsigned*)&a, ub = *(unsigned*)&b, ur;
    asm("v_pk_max_f16 %0, %1, %2" : "=v"(ur) : "v"(ua), "v"(ub));
    return *(__half2*)&ur;
}
__device__ __forceinline__ __half2 u2h2(unsigned u) { return *(__half2*)&u; }

// tree product of 8 f16x2 literals (dep depth 3, same op count as chain)
__device__ __forceinline__ __half2 prod8(unsigned a0, unsigned a1, unsigned a2, unsigned a3,
                                         unsigned a4, unsigned a5, unsigned a6, unsigned a7) {
    __half2 q01 = __hmul2(u2h2(a0), u2h2(a1));
    __half2 q23 = __hmul2(u2h2(a2), u2h2(a3));
    __half2 q45 = __hmul2(u2h2(a4), u2h2(a5));
    __half2 q67 = __hmul2(u2h2(a6), u2h2(a7));
    return __hmul2(__hmul2(q01, q23), __hmul2(q45, q67));
}

// pack 8 literal slots ((f<<1)|sgn) of one conjunction into a uint4 (8 x u16)
__device__ __forceinline__ uint4 pack8(int4 f0, int4 f1, int4 s0, int4 s1) {
    unsigned t0 = ((unsigned)(f0.x << 1) | (s0.x > 0 ? 1u : 0u)) & 0xFFFFu;
    unsigned t1 = ((unsigned)(f0.y << 1) | (s0.y > 0 ? 1u : 0u)) & 0xFFFFu;
    unsigned t2 = ((unsigned)(f0.z << 1) | (s0.z > 0 ? 1u : 0u)) & 0xFFFFu;
    unsigned t3 = ((unsigned)(f0.w << 1) | (s0.w > 0 ? 1u : 0u)) & 0xFFFFu;
    unsigned t4 = ((unsigned)(f1.x << 1) | (s1.x > 0 ? 1u : 0u)) & 0xFFFFu;
    unsigned t5 = ((unsigned)(f1.y << 1) | (s1.y > 0 ? 1u : 0u)) & 0xFFFFu;
    unsigned t6 = ((unsigned)(f1.z << 1) | (s1.z > 0 ? 1u : 0u)) & 0xFFFFu;
    unsigned t7 = ((unsigned)(f1.w << 1) | (s1.w > 0 ? 1u : 0u)) & 0xFFFFu;
    uint4 p;
    p.x = t0 | (t1 << 16);
    p.y = t2 | (t3 << 16);
    p.z = t4 | (t5 << 16);
    p.w = t6 | (t7 << 16);
    return p;
}

__device__ __forceinline__ uint4 build_kl(const int* __restrict__ feat,
                                          const int* __restrict__ sign, int c) {
    const int4* fq = (const int4*)(feat + c * T_);
    const int4* sq = (const int4*)(sign + c * T_);
    return pack8(fq[0], fq[1], sq[0], sq[1]);
}

// gather 8 literals (8 x ds_read_b128) of packed conjunction P
#define GATHER8(P)                                                   \
    uint4 g0 = xs4[(P).x & 0xFFFFu], g1 = xs4[(P).x >> 16],          \
          g2 = xs4[(P).y & 0xFFFFu], g3 = xs4[(P).y >> 16],          \
          g4 = xs4[(P).z & 0xFFFFu], g5 = xs4[(P).z >> 16],          \
          g6 = xs4[(P).w & 0xFFFFu], g7 = xs4[(P).w >> 16];

#define PROD_INIT(P, RA, RB, RC, RD)                                 \
    { GATHER8(P)                                                     \
      RA = prod8(g0.x,g1.x,g2.x,g3.x,g4.x,g5.x,g6.x,g7.x);          \
      RB = prod8(g0.y,g1.y,g2.y,g3.y,g4.y,g5.y,g6.y,g7.y);          \
      RC = prod8(g0.z,g1.z,g2.z,g3.z,g4.z,g5.z,g6.z,g7.z);          \
      RD = prod8(g0.w,g1.w,g2.w,g3.w,g4.w,g5.w,g6.w,g7.w); }

#define PROD_MAX(P, RA, RB, RC, RD)                                  \
    { GATHER8(P)                                                     \
      RA = h2max(RA, prod8(g0.x,g1.x,g2.x,g3.x,g4.x,g5.x,g6.x,g7.x)); \
      RB = h2max(RB, prod8(g0.y,g1.y,g2.y,g3.y,g4.y,g5.y,g6.y,g7.y)); \
      RC = h2max(RC, prod8(g0.z,g1.z,g2.z,g3.z,g4.z,g5.z,g6.z,g7.z)); \
      RD = h2max(RD, prod8(g0.w,g1.w,g2.w,g3.w,g4.w,g5.w,g6.w,g7.w)); }

// ---------------------------------------------------------------------------
// Fully fused: one 1024-thread block per 8 batch rows; grid=256 = 1 block/CU.
// LDS: one uint4 per (f,sgn) slot = 8 rows f16 = 128 KB.
// Order: stage x -> inline klit build (L2 latency hides under other waves'
// staging + barrier) -> barrier -> 64 b128 gathers with tree-mul products and
// even/odd dual max accumulators. No workspace, single launch.
// ---------------------------------------------------------------------------
__global__ __launch_bounds__(TPB, 4) void dnf_fused(
    const float* __restrict__ x,
    const int* __restrict__ feat,
    const int* __restrict__ sign,
    const int* __restrict__ class_conj,
    float* __restrict__ out)
{
    __shared__ __align__(16) uint4 xs4[F_ * 2];   // 128 KB: slot = (f<<1)|sgn

    const int b0  = blockIdx.x * RROWS;
    const int tid = threadIdx.x;
    const int kk  = tid;                          // one class per thread

    // ---- stage 8 rows of x as dual f16 table ----
    for (int f = tid; f < F_; f += TPB) {
        float v0 = x[(size_t)(b0 + 0) * F_ + f];
        float v1 = x[(size_t)(b0 + 1) * F_ + f];
        float v2 = x[(size_t)(b0 + 2) * F_ + f];
        float v3 = x[(size_t)(b0 + 3) * F_ + f];
        float v4 = x[(size_t)(b0 + 4) * F_ + f];
        float v5 = x[(size_t)(b0 + 5) * F_ + f];
        float v6 = x[(size_t)(b0 + 6) * F_ + f];
        float v7 = x[(size_t)(b0 + 7) * F_ + f];
        __half2 n01 = __floats2half2_rn(1.0f - v0, 1.0f - v1);
        __half2 n23 = __floats2half2_rn(1.0f - v2, 1.0f - v3);
        __half2 n45 = __floats2half2_rn(1.0f - v4, 1.0f - v5);
        __half2 n67 = __floats2half2_rn(1.0f - v6, 1.0f - v7);
        __half2 p01 = __floats2half2_rn(v0, v1);
        __half2 p23 = __floats2half2_rn(v2, v3);
        __half2 p45 = __floats2half2_rn(v4, v5);
        __half2 p67 = __floats2half2_rn(v6, v7);
        uint4 neg, pos;
        neg.x = *(unsigned*)&n01; neg.y = *(unsigned*)&n23;
        neg.z = *(unsigned*)&n45; neg.w = *(unsigned*)&n67;
        pos.x = *(unsigned*)&p01; pos.y = *(unsigned*)&p23;
        pos.z = *(unsigned*)&p45; pos.w = *(unsigned*)&p67;
        xs4[(f << 1) | 0] = neg;
        xs4[(f << 1) | 1] = pos;
    }

    // ---- inline klit build (replaces the separate prepass kernel) ----
    int4 cc0 = ((const int4*)(class_conj + kk * S_))[0];
    int4 cc1 = ((const int4*)(class_conj + kk * S_))[1];
    uint4 kl0 = build_kl(feat, sign, cc0.x);
    uint4 kl1 = build_kl(feat, sign, cc0.y);
    uint4 kl2 = build_kl(feat, sign, cc0.z);
    uint4 kl3 = build_kl(feat, sign, cc0.w);
    uint4 kl4 = build_kl(feat, sign, cc1.x);
    uint4 kl5 = build_kl(feat, sign, cc1.y);
    uint4 kl6 = build_kl(feat, sign, cc1.z);
    uint4 kl7 = build_kl(feat, sign, cc1.w);

    __syncthreads();

    // ---- 8 disjunct steps, even/odd dual accumulators ----
    __half2 eA, eB, eC, eD, oA, oB, oC, oD;
    PROD_INIT(kl0, eA, eB, eC, eD);
    PROD_INIT(kl1, oA, oB, oC, oD);
    PROD_MAX (kl2, eA, eB, eC, eD);
    PROD_MAX (kl3, oA, oB, oC, oD);
    PROD_MAX (kl4, eA, eB, eC, eD);
    PROD_MAX (kl5, oA, oB, oC, oD);
    PROD_MAX (kl6, eA, eB, eC, eD);
    PROD_MAX (kl7, oA, oB, oC, oD);
    __half2 ma = h2max(eA, oA), mb = h2max(eB, oB);
    __half2 mc = h2max(eC, oC), md = h2max(eD, oD);

    float2 f;
    f = __half22float2(ma); out[(size_t)(b0+0)*K_+kk] = f.x; out[(size_t)(b0+1)*K_+kk] = f.y;
    f = __half22float2(mb); out[(size_t)(b0+2)*K_+kk] = f.x; out[(size_t)(b0+3)*K_+kk] = f.y;
    f = __half22float2(mc); out[(size_t)(b0+4)*K_+kk] = f.x; out[(size_t)(b0+5)*K_+kk] = f.y;
    f = __half22float2(md); out[(size_t)(b0+6)*K_+kk] = f.x; out[(size_t)(b0+7)*K_+kk] = f.y;
}

extern "C" void kernel_launch(void* const* d_in, const int* in_sizes, int n_in,
                              void* d_out, int out_size, void* d_ws, size_t ws_size,
                              hipStream_t stream) {
    const float* x  = (const float*)d_in[0];
    const int* feat = (const int*)d_in[1];
    const int* sign = (const int*)d_in[2];
    const int* ccj  = (const int*)d_in[3];
    float* out      = (float*)d_out;

    dnf_fused<<<B_ / RROWS, TPB, 0, stream>>>(x, feat, sign, ccj, out);
}

// Round 16
// 21.328 us; speedup vs baseline: 1.8566x; 1.8566x over previous
//
#include <hip/hip_runtime.h>
#include <hip/hip_fp16.h>

#define B_ 2048
#define F_ 4096
#define C_ 8192
#define T_ 8
#define K_ 1024
#define S_ 8
#define RROWS 8
#define TPB 1024

// ---------------------------------------------------------------------------
// Prepass: klit[s][k] = 8 packed u16 LDS-slot indices ((f<<1)|sgn) of the
// literals of conjunction class_conj[k][s].  Transposed layout so the main
// kernel's step-s load is perfectly coalesced across lanes (16 B x lane-consecutive).
// ---------------------------------------------------------------------------
__global__ void build_klit_kernel(const int* __restrict__ feat,
                                  const int* __restrict__ sign,
                                  const int* __restrict__ class_conj,
                                  uint4* __restrict__ klit) {
    int j = blockIdx.x * blockDim.x + threadIdx.x;   // j = s*K_ + k
    if (j >= K_ * S_) return;
    int k = j & (K_ - 1);
    int s = j >> 10;                                  // K_=1024
    int c = class_conj[k * S_ + s];
    const int* fr = feat + c * T_;
    const int* sr = sign + c * T_;
    unsigned t[T_];
    #pragma unroll
    for (int i = 0; i < T_; ++i)
        t[i] = (unsigned)((fr[i] << 1) | (sr[i] > 0 ? 1 : 0)) & 0xFFFFu;
    uint4 p;
    p.x = t[0] | (t[1] << 16);
    p.y = t[2] | (t[3] << 16);
    p.z = t[4] | (t[5] << 16);
    p.w = t[6] | (t[7] << 16);
    klit[j] = p;
}

// packed f16 max: ROCm 7.2 lacks __hmax2; gfx950 has v_pk_max_f16
__device__ __forceinline__ __half2 h2max(__half2 a, __half2 b) {
    unsigned int ua = *(unsigned int*)&a, ub = *(unsigned int*)&b, ur;
    asm("v_pk_max_f16 %0, %1, %2" : "=v"(ur) : "v"(ua), "v"(ub));
    return *(__half2*)&ur;
}

__device__ __forceinline__ __half2 u2h2(unsigned int u) { return *(__half2*)&u; }

// one literal for 8 rows: ONE ds_read_b128 at slot index (direct LDS indexing)
#define LIT_INIT(SLOT)                                              \
    { uint4 g = xs4[SLOT];                                          \
      pa = u2h2(g.x); pb = u2h2(g.y); pc = u2h2(g.z); pd = u2h2(g.w); }
#define LIT_MUL(SLOT)                                               \
    { uint4 g = xs4[SLOT];                                          \
      pa = __hmul2(pa, u2h2(g.x)); pb = __hmul2(pb, u2h2(g.y));     \
      pc = __hmul2(pc, u2h2(g.z)); pd = __hmul2(pd, u2h2(g.w)); }

// ---------------------------------------------------------------------------
// Fused kernel: one 1024-thread block per 8 batch rows; grid=256 = 1 block/CU.
// LDS: xs[f][s][8 rows] f16 = 32 B/feature = 128 KB (one uint4 per (f,s)).
// Each literal is ONE ds_read_b128 serving all 8 rows, sign folded into slot.
// Index stream: klit[s][kk] — coalesced 16 B/lane, no random global gathers.
// ---------------------------------------------------------------------------
__global__ __launch_bounds__(TPB, 4) void dnf_kernel(
    const float* __restrict__ x,
    const uint4* __restrict__ klit,
    float* __restrict__ out)
{
    __shared__ __align__(16) uint4 xs4[F_ * 2];   // 128 KB: slot = (f<<1)|s

    const int b0  = blockIdx.x * RROWS;
    const int tid = threadIdx.x;

    // ---- stage 8 rows of x as dual f16 table ----
    for (int f = tid; f < F_; f += TPB) {
        float v0 = x[(size_t)(b0 + 0) * F_ + f];
        float v1 = x[(size_t)(b0 + 1) * F_ + f];
        float v2 = x[(size_t)(b0 + 2) * F_ + f];
        float v3 = x[(size_t)(b0 + 3) * F_ + f];
        float v4 = x[(size_t)(b0 + 4) * F_ + f];
        float v5 = x[(size_t)(b0 + 5) * F_ + f];
        float v6 = x[(size_t)(b0 + 6) * F_ + f];
        float v7 = x[(size_t)(b0 + 7) * F_ + f];
        __half2 n01 = __floats2half2_rn(1.0f - v0, 1.0f - v1);
        __half2 n23 = __floats2half2_rn(1.0f - v2, 1.0f - v3);
        __half2 n45 = __floats2half2_rn(1.0f - v4, 1.0f - v5);
        __half2 n67 = __floats2half2_rn(1.0f - v6, 1.0f - v7);
        __half2 p01 = __floats2half2_rn(v0, v1);
        __half2 p23 = __floats2half2_rn(v2, v3);
        __half2 p45 = __floats2half2_rn(v4, v5);
        __half2 p67 = __floats2half2_rn(v6, v7);
        uint4 neg, pos;
        neg.x = *(unsigned*)&n01; neg.y = *(unsigned*)&n23;
        neg.z = *(unsigned*)&n45; neg.w = *(unsigned*)&n67;
        pos.x = *(unsigned*)&p01; pos.y = *(unsigned*)&p23;
        pos.z = *(unsigned*)&p45; pos.w = *(unsigned*)&p67;
        xs4[(f << 1) | 0] = neg;
        xs4[(f << 1) | 1] = pos;
    }
    __syncthreads();

    const int kk = tid;                          // one class per thread

    __half2 ma, mb, mc, md;
    #pragma unroll
    for (int s = 0; s < S_; ++s) {
        uint4 p = klit[s * K_ + kk];             // coalesced index load
        __half2 pa, pb, pc, pd;
        LIT_INIT(p.x & 0xFFFFu);
        LIT_MUL (p.x >> 16);
        LIT_MUL (p.y & 0xFFFFu);
        LIT_MUL (p.y >> 16);
        LIT_MUL (p.z & 0xFFFFu);
        LIT_MUL (p.z >> 16);
        LIT_MUL (p.w & 0xFFFFu);
        LIT_MUL (p.w >> 16);
        if (s == 0) { ma = pa; mb = pb; mc = pc; md = pd; }
        else {
            ma = h2max(ma, pa); mb = h2max(mb, pb);
            mc = h2max(mc, pc); md = h2max(md, pd);
        }
    }

    float2 f;
    f = __half22float2(ma); out[(size_t)(b0+0)*K_+kk] = f.x; out[(size_t)(b0+1)*K_+kk] = f.y;
    f = __half22float2(mb); out[(size_t)(b0+2)*K_+kk] = f.x; out[(size_t)(b0+3)*K_+kk] = f.y;
    f = __half22float2(mc); out[(size_t)(b0+4)*K_+kk] = f.x; out[(size_t)(b0+5)*K_+kk] = f.y;
    f = __half22float2(md); out[(size_t)(b0+6)*K_+kk] = f.x; out[(size_t)(b0+7)*K_+kk] = f.y;
}

// ---------------------------------------------------------------------------
// Fallback (no workspace): reads feat/sign/class_conj directly.
// ---------------------------------------------------------------------------
__global__ __launch_bounds__(TPB, 4) void dnf_kernel_nows(
    const float* __restrict__ x,
    const int* __restrict__ feat,
    const int* __restrict__ sign,
    const int* __restrict__ class_conj,
    float* __restrict__ out)
{
    __shared__ __align__(16) uint4 xs4[F_ * 2];   // 128 KB

    const int b0  = blockIdx.x * RROWS;
    const int tid = threadIdx.x;

    for (int f = tid; f < F_; f += TPB) {
        float v0 = x[(size_t)(b0 + 0) * F_ + f];
        float v1 = x[(size_t)(b0 + 1) * F_ + f];
        float v2 = x[(size_t)(b0 + 2) * F_ + f];
        float v3 = x[(size_t)(b0 + 3) * F_ + f];
        float v4 = x[(size_t)(b0 + 4) * F_ + f];
        float v5 = x[(size_t)(b0 + 5) * F_ + f];
        float v6 = x[(size_t)(b0 + 6) * F_ + f];
        float v7 = x[(size_t)(b0 + 7) * F_ + f];
        __half2 n01 = __floats2half2_rn(1.0f - v0, 1.0f - v1);
        __half2 n23 = __floats2half2_rn(1.0f - v2, 1.0f - v3);
        __half2 n45 = __floats2half2_rn(1.0f - v4, 1.0f - v5);
        __half2 n67 = __floats2half2_rn(1.0f - v6, 1.0f - v7);
        __half2 p01 = __floats2half2_rn(v0, v1);
        __half2 p23 = __floats2half2_rn(v2, v3);
        __half2 p45 = __floats2half2_rn(v4, v5);
        __half2 p67 = __floats2half2_rn(v6, v7);
        uint4 neg, pos;
        neg.x = *(unsigned*)&n01; neg.y = *(unsigned*)&n23;
        neg.z = *(unsigned*)&n45; neg.w = *(unsigned*)&n67;
        pos.x = *(unsigned*)&p01; pos.y = *(unsigned*)&p23;
        pos.z = *(unsigned*)&p45; pos.w = *(unsigned*)&p67;
        xs4[(f << 1) | 0] = neg;
        xs4[(f << 1) | 1] = pos;
    }
    __syncthreads();

    const int kk = tid;
    const int4* cc = (const int4*)(class_conj + kk * S_);
    int4 a0 = cc[0], a1 = cc[1];
    int idx[S_] = {a0.x, a0.y, a0.z, a0.w, a1.x, a1.y, a1.z, a1.w};

    __half2 ma, mb, mc, md;
    #pragma unroll
    for (int s = 0; s < S_; ++s) {
        int c = idx[s];
        const int4* fq = (const int4*)(feat + c * T_);
        const int4* sq = (const int4*)(sign + c * T_);
        int4 f0 = fq[0], f1 = fq[1];
        int4 s0 = sq[0], s1 = sq[1];
        __half2 pa, pb, pc, pd;
        unsigned o;
        o = (f0.x << 1) | (s0.x > 0 ? 1 : 0); LIT_INIT(o);
        o = (f0.y << 1) | (s0.y > 0 ? 1 : 0); LIT_MUL(o);
        o = (f0.z << 1) | (s0.z > 0 ? 1 : 0); LIT_MUL(o);
        o = (f0.w << 1) | (s0.w > 0 ? 1 : 0); LIT_MUL(o);
        o = (f1.x << 1) | (s1.x > 0 ? 1 : 0); LIT_MUL(o);
        o = (f1.y << 1) | (s1.y > 0 ? 1 : 0); LIT_MUL(o);
        o = (f1.z << 1) | (s1.z > 0 ? 1 : 0); LIT_MUL(o);
        o = (f1.w << 1) | (s1.w > 0 ? 1 : 0); LIT_MUL(o);
        if (s == 0) { ma = pa; mb = pb; mc = pc; md = pd; }
        else {
            ma = h2max(ma, pa); mb = h2max(mb, pb);
            mc = h2max(mc, pc); md = h2max(md, pd);
        }
    }

    float2 f;
    f = __half22float2(ma); out[(size_t)(b0+0)*K_+kk] = f.x; out[(size_t)(b0+1)*K_+kk] = f.y;
    f = __half22float2(mb); out[(size_t)(b0+2)*K_+kk] = f.x; out[(size_t)(b0+3)*K_+kk] = f.y;
    f = __half22float2(mc); out[(size_t)(b0+4)*K_+kk] = f.x; out[(size_t)(b0+5)*K_+kk] = f.y;
    f = __half22float2(md); out[(size_t)(b0+6)*K_+kk] = f.x; out[(size_t)(b0+7)*K_+kk] = f.y;
}

extern "C" void kernel_launch(void* const* d_in, const int* in_sizes, int n_in,
                              void* d_out, int out_size, void* d_ws, size_t ws_size,
                              hipStream_t stream) {
    const float* x  = (const float*)d_in[0];
    const int* feat = (const int*)d_in[1];
    const int* sign = (const int*)d_in[2];
    const int* ccj  = (const int*)d_in[3];
    float* out      = (float*)d_out;

    const size_t klit_bytes = (size_t)K_ * S_ * sizeof(uint4);  // 128 KB
    if (ws_size >= klit_bytes) {
        uint4* klit = (uint4*)d_ws;
        build_klit_kernel<<<(K_ * S_ + 255) / 256, 256, 0, stream>>>(feat, sign, ccj, klit);
        dnf_kernel<<<B_ / RROWS, TPB, 0, stream>>>(x, klit, out);
    } else {
        dnf_kernel_nows<<<B_ / RROWS, TPB, 0, stream>>>(x, feat, sign, ccj, out);
    }
}